// Round 4
// baseline (24.983 us; speedup 1.0000x reference)
//
#include <hip/hip_runtime.h>

// Cost volume loss: pred/target (8,3,512,512) f32.
// Per pixel: min over 5x5 offsets (zero-padded target) of mean_C |pred - patch|,
// then global mean. Output: single f32 scalar.
//
// Block = 512 cols x 8 rows. Target halo tile (12 rows x 3ch x 512) staged in
// 72KB dynamic LDS via global_load_lds (async DMA). Threads: 4 cols x 4 rows,
// 128 col-threads x 2 row-groups. Grid = 8 n * 64 hgrps = 512 blocks.

#define H_DIM 512
#define W_DIM 512
#define N_DIM 8
#define C_DIM 3
#define HW (H_DIM * W_DIM)
#define CHW (C_DIM * HW)
#define NPIX (N_DIM * HW)
#define NBLOCKS 512
#define LDS_BYTES (C_DIM * 12 * W_DIM * 4)  // 73728 = 72 KiB

typedef const float __attribute__((address_space(1)))* gas_ptr;
typedef float __attribute__((address_space(3)))* las_ptr;

__global__ __launch_bounds__(256, 2) void cvl_main(const float* __restrict__ pred,
                                                   const float* __restrict__ targ,
                                                   float* __restrict__ partial) {
    extern __shared__ float lds[];    // layout: [c][r][512], r = hh - (hbase-2)
    const int tid   = threadIdx.x;
    const int lane  = tid & 63;
    const int wv    = tid >> 6;       // wave 0..3
    const int col   = tid & 127;      // 0..127
    const int rg    = tid >> 7;       // 0..1
    const int bid   = blockIdx.x;     // 0..511
    const int n     = bid >> 6;       // 0..7
    const int hg    = bid & 63;       // 0..63
    const int hbase = hg * 8;
    const int h0    = hbase + rg * 4; // first of this thread's 4 rows
    const int w0    = col * 4;        // first of this thread's 4 cols

    const size_t nbase = (size_t)n * CHW;

    // ---- pred: 4 rows x 3 channels x 4 pixels, direct to registers (issued
    // first so they overlap the LDS staging DMA) ----
    float pf[4][3][4];
#pragma unroll
    for (int r = 0; r < 4; ++r) {
#pragma unroll
        for (int c = 0; c < 3; ++c) {
            const float4 v = *(const float4*)(pred + nbase + (size_t)c * HW +
                                              (size_t)(h0 + r) * W_DIM + w0);
            pf[r][c][0] = v.x; pf[r][c][1] = v.y; pf[r][c][2] = v.z; pf[r][c][3] = v.w;
        }
    }

    // ---- stage target tile: 12 rows x 3 ch x 512 floats = 72 chunks of 1KB,
    // wave-strided; LDS dest is wave-uniform base + lane*16 (linear) ----
#pragma unroll
    for (int it = 0; it < 18; ++it) {
        const int chunk = it * 4 + wv;       // 0..71, uniform per wave
        const int c   = chunk / 24;          // channel
        const int rem = chunk % 24;
        const int r   = rem >> 1;            // tile row 0..11
        const int hf  = rem & 1;             // half-row 0/1
        const int hh  = hbase - 2 + r;
        if (hh >= 0 && hh < H_DIM) {         // uniform per wave -> scalar branch
            const float* g = targ + nbase + (size_t)c * HW + (size_t)hh * W_DIM +
                             hf * 256 + lane * 4;
            float* l = lds + ((c * 12 + r) * W_DIM + hf * 256);
            __builtin_amdgcn_global_load_lds((gas_ptr)g, (las_ptr)l, 16, 0, 0);
        }
    }
    asm volatile("s_waitcnt vmcnt(0)" ::: "memory");
    __syncthreads();

    // Channel-sum |pred| (value of s at any zero-padded offset)
    float soob[4][4];
#pragma unroll
    for (int r = 0; r < 4; ++r)
#pragma unroll
        for (int px = 0; px < 4; ++px)
            soob[r][px] = fabsf(pf[r][0][px]) + fabsf(pf[r][1][px]) + fabsf(pf[r][2][px]);

    float best[4][4];
#pragma unroll
    for (int r = 0; r < 4; ++r)
#pragma unroll
        for (int px = 0; px < 4; ++px)
            best[r][px] = 3.0e38f;

    const bool wlo = (w0 == 0);            // left image edge lane
    const bool whi = (w0 == W_DIM - 4);    // right image edge lane
    const int offm = (w0 - 4 < 0) ? 0 : (w0 - 4);
    const int offp = (w0 + 4 > W_DIM - 4) ? (W_DIM - 4) : (w0 + 4);

    // ---- 8 target rows per thread, now read from LDS ----
#pragma unroll
    for (int j = 0; j < 8; ++j) {
        const int r  = rg * 4 + j;           // tile row index
        const int hh = h0 - 2 + j;
        if (hh >= 0 && hh < H_DIM) {         // uniform per wave
            float tw[3][12];
#pragma unroll
            for (int c = 0; c < 3; ++c) {
                const float* rowp = lds + (c * 12 + r) * W_DIM;
                const float4 a = *(const float4*)(rowp + offm);
                const float4 b = *(const float4*)(rowp + w0);
                const float4 d = *(const float4*)(rowp + offp);
                tw[c][0] = a.x;  tw[c][1] = a.y;  tw[c][2]  = a.z;  tw[c][3]  = a.w;
                tw[c][4] = b.x;  tw[c][5] = b.y;  tw[c][6]  = b.z;  tw[c][7]  = b.w;
                tw[c][8] = d.x;  tw[c][9] = d.y;  tw[c][10] = d.z;  tw[c][11] = d.w;
            }
#pragma unroll
            for (int orow = 0; orow < 4; ++orow) {
                const int di = j - 2 - orow;          // compile-time after unroll
                if (di >= -2 && di <= 2) {
#pragma unroll
                    for (int px = 0; px < 4; ++px) {
#pragma unroll
                        for (int dj = -2; dj <= 2; ++dj) {
                            const int ix = 4 + px + dj;  // 2..9
                            float s = fabsf(pf[orow][0][px] - tw[0][ix])
                                    + fabsf(pf[orow][1][px] - tw[1][ix])
                                    + fabsf(pf[orow][2][px] - tw[2][ix]);
                            if (px + dj < 0)      s = wlo ? soob[orow][px] : s;
                            else if (px + dj > 3) s = whi ? soob[orow][px] : s;
                            best[orow][px] = fminf(best[orow][px], s);
                        }
                    }
                }
            }
        } else {
            // whole target row is zero-pad: every dj contributes soob
#pragma unroll
            for (int orow = 0; orow < 4; ++orow) {
                const int di = j - 2 - orow;
                if (di >= -2 && di <= 2) {
#pragma unroll
                    for (int px = 0; px < 4; ++px)
                        best[orow][px] = fminf(best[orow][px], soob[orow][px]);
                }
            }
        }
    }

    // ---- reduce: 16 pixels -> thread, wave shuffle, LDS, one store/block ----
    float v = 0.0f;
#pragma unroll
    for (int r = 0; r < 4; ++r)
#pragma unroll
        for (int px = 0; px < 4; ++px)
            v += best[r][px];

#pragma unroll
    for (int o = 32; o > 0; o >>= 1) v += __shfl_down(v, o, 64);

    __shared__ float ws[4];
    if (lane == 0) ws[wv] = v;
    __syncthreads();
    if (tid == 0) {
        partial[bid] = ws[0] + ws[1] + ws[2] + ws[3];
    }
}

__global__ __launch_bounds__(256) void cvl_final(const float* __restrict__ partial,
                                                 float* __restrict__ out) {
    const int tid = threadIdx.x;
    double v = (double)partial[tid] + (double)partial[tid + 256];
#pragma unroll
    for (int o = 32; o > 0; o >>= 1) v += __shfl_down(v, o, 64);

    __shared__ double ws[4];
    const int lane = tid & 63;
    const int wid  = tid >> 6;
    if (lane == 0) ws[wid] = v;
    __syncthreads();
    if (tid == 0) {
        const double s = ws[0] + ws[1] + ws[2] + ws[3];
        out[0] = (float)(s / (3.0 * (double)NPIX));
    }
}

extern "C" void kernel_launch(void* const* d_in, const int* in_sizes, int n_in,
                              void* d_out, int out_size, void* d_ws, size_t ws_size,
                              hipStream_t stream) {
    const float* pred = (const float*)d_in[0];
    const float* targ = (const float*)d_in[1];
    float* out = (float*)d_out;
    float* partial = (float*)d_ws;

    // Raise dynamic-LDS cap to 72KB (not a stream op; capture-safe, idempotent).
    hipFuncSetAttribute((const void*)cvl_main,
                        hipFuncAttributeMaxDynamicSharedMemorySize, LDS_BYTES);

    cvl_main<<<NBLOCKS, 256, LDS_BYTES, stream>>>(pred, targ, partial);
    cvl_final<<<1, 256, 0, stream>>>(partial, out);
}